// Round 3
// baseline (591.006 us; speedup 1.0000x reference)
//
#include <hip/hip_runtime.h>
#include <math.h>

// Problem constants (match reference)
#define NUM_CLASSES 80
#define ALPHA 0.25f
#define BETA 0.11f
#define POS_THR 0.5f
#define NEG_THR 0.4f
#define B_CNT 8
#define A_CNT 98304
#define G_CNT 32

#define FOCAL_BLOCKS 15360   // 15360*256*4 float4 = 15,728,640 = B*A*80/4 exactly

// ws layout:
//   [0]  float cls_sum
//   [4]  float reg_sum
//   [8]  float num_pos
//   [16] unsigned char valid[B*A]   (1 = cls_t>=0 i.e. contributes to focal sum)

__device__ __forceinline__ float block_reduce_sum(float v, float* s) {
    #pragma unroll
    for (int off = 32; off > 0; off >>= 1) v += __shfl_down(v, off, 64);
    const int wave = threadIdx.x >> 6;
    if ((threadIdx.x & 63) == 0) s[wave] = v;
    __syncthreads();
    return (threadIdx.x == 0) ? (s[0] + s[1] + s[2] + s[3]) : 0.0f;
}

// focal term for t=0 (background class slot), HW transcendentals only:
//   e = exp(-|x|), prob = sigmoid(x), softplus(x) = max(x,0)+log(1+e)
//   focal0 = (1-ALPHA) * prob^2 * softplus(x)
__device__ __forceinline__ float focal0(float x) {
    const float e  = __expf(-fabsf(x));
    const float op = 1.0f + e;
    const float r  = __builtin_amdgcn_rcpf(op);
    const float prob = (x >= 0.0f) ? r : e * r;
    const float sp = fmaxf(x, 0.0f) + __logf(op);
    return 0.75f * prob * prob * sp;
}

// focal term for t=1 (the fg anchor's target class slot):
//   focal1 = ALPHA * (1-prob)^2 * softplus(-x)
__device__ __forceinline__ float focal1(float x) {
    const float e  = __expf(-fabsf(x));
    const float op = 1.0f + e;
    const float r  = __builtin_amdgcn_rcpf(op);
    const float prob = (x >= 0.0f) ? r : e * r;
    const float q  = 1.0f - prob;
    const float sp = fmaxf(-x, 0.0f) + __logf(op);
    return 0.25f * q * q * sp;
}

__global__ __launch_bounds__(256) void match_kernel(
    const float* __restrict__ cls_pred,   // [B,A,80] (for fg correction term)
    const float* __restrict__ reg_pred,   // [B,A,4]
    const float* __restrict__ anchors,    // [A,4]
    const float* __restrict__ gt_boxes,   // [B,G,4]
    const int*   __restrict__ gt_labels,  // [B,G]
    unsigned char* __restrict__ valid_out,// [B*A]
    float* __restrict__ accum)
{
    __shared__ float4 s_gt[G_CNT];
    __shared__ int    s_lab[G_CNT];
    __shared__ float  s_red[4];

    const int blocks_per_batch = A_CNT / 256;           // 384, exact
    const int b = blockIdx.x / blocks_per_batch;
    const int a = (blockIdx.x % blocks_per_batch) * 256 + threadIdx.x;

    if (threadIdx.x < G_CNT) {
        s_gt[threadIdx.x]  = ((const float4*)gt_boxes)[b * G_CNT + threadIdx.x];
        s_lab[threadIdx.x] = gt_labels[b * G_CNT + threadIdx.x];
    }
    __syncthreads();

    const float4 an = ((const float4*)anchors)[a];
    const float aw = an.z - an.x;
    const float ah = an.w - an.y;
    const float area_a = aw * ah;

    float best = -1.0f;
    int bidx = 0;
    #pragma unroll
    for (int g = 0; g < G_CNT; ++g) {
        const float4 gb = s_gt[g];
        const float ltx = fmaxf(an.x, gb.x);
        const float lty = fmaxf(an.y, gb.y);
        const float rbx = fminf(an.z, gb.z);
        const float rby = fminf(an.w, gb.w);
        const float w = fmaxf(rbx - ltx, 0.0f);
        const float h = fmaxf(rby - lty, 0.0f);
        const float inter = w * h;
        const float area_g = (gb.z - gb.x) * (gb.w - gb.y);
        const float iou = inter / (area_a + area_g - inter);
        if (iou > best) { best = iou; bidx = g; }   // first-max == jnp argmax
    }

    const bool pos = (best >= POS_THR);
    const bool vld = pos || (best < NEG_THR);           // cls_t >= 0
    valid_out[b * A_CNT + a] = vld ? 1 : 0;

    float regsum = 0.0f;
    float clsdelta = 0.0f;
    if (pos) {
        const float4 gb = s_gt[bidx];
        const float gw = gb.z - gb.x;
        const float gh = gb.w - gb.y;
        const float gx = gb.x + 0.5f * gw;
        const float gy = gb.y + 0.5f * gh;
        const float ax = an.x + 0.5f * aw;
        const float ay = an.y + 0.5f * ah;
        const float t0 = (gx - ax) / aw;
        const float t1 = (gy - ay) / ah;
        const float t2 = __logf(gw / aw);
        const float t3 = __logf(gh / ah);
        const float4 rp = ((const float4*)reg_pred)[b * A_CNT + a];
        const float d0 = fabsf(rp.x - t0);
        const float d1 = fabsf(rp.y - t1);
        const float d2 = fabsf(rp.z - t2);
        const float d3 = fabsf(rp.w - t3);
        const float s0 = (d0 < BETA) ? 0.5f * d0 * d0 / BETA : d0 - 0.5f * BETA;
        const float s1 = (d1 < BETA) ? 0.5f * d1 * d1 / BETA : d1 - 0.5f * BETA;
        const float s2 = (d2 < BETA) ? 0.5f * d2 * d2 / BETA : d2 - 0.5f * BETA;
        const float s3 = (d3 < BETA) ? 0.5f * d3 * d3 / BETA : d3 - 0.5f * BETA;
        regsum = s0 + s1 + s2 + s3;

        // fg correction: the target-class element uses focal1 instead of focal0.
        const int lab = s_lab[bidx];                    // 1..80
        const float xt = cls_pred[(size_t)(b * A_CNT + a) * NUM_CLASSES + (lab - 1)];
        clsdelta = focal1(xt) - focal0(xt);
    }

    float rs = block_reduce_sum(regsum, s_red);
    if (threadIdx.x == 0 && rs != 0.0f) atomicAdd(&accum[1], rs);
    __syncthreads();
    float cnt = block_reduce_sum(pos ? 1.0f : 0.0f, s_red);
    if (threadIdx.x == 0 && cnt != 0.0f) atomicAdd(&accum[2], cnt);
    __syncthreads();
    float cd = block_reduce_sum(clsdelta, s_red);
    if (threadIdx.x == 0 && cd != 0.0f) atomicAdd(&accum[0], cd);
}

__global__ __launch_bounds__(256) void focal_kernel(
    const float* __restrict__ cls_pred,        // [B*A*80]
    const unsigned char* __restrict__ valid,   // [B*A]
    float* __restrict__ accum)
{
    __shared__ float s_red[4];
    const int stride = FOCAL_BLOCKS * 256;
    int i = blockIdx.x * 256 + threadIdx.x;
    float sum = 0.0f;
    #pragma unroll
    for (int k = 0; k < 4; ++k, i += stride) {
        const int anchor = i / (NUM_CLASSES / 4);      // magic-mul, cheap
        if (valid[anchor]) {
            const float4 x4 = ((const float4*)cls_pred)[i];
            sum += focal0(x4.x);
            sum += focal0(x4.y);
            sum += focal0(x4.z);
            sum += focal0(x4.w);
        }
    }
    const float bs = block_reduce_sum(sum, s_red);
    if (threadIdx.x == 0 && bs != 0.0f) atomicAdd(&accum[0], bs);
}

__global__ void finalize_kernel(const float* __restrict__ accum, float* __restrict__ out) {
    const float cs = accum[0];
    const float rs = accum[1];
    const float np = accum[2];
    const float denom = fmaxf(np, 1.0f);
    const float cl = (np > 0.0f) ? cs / denom : cs;
    const float rl = (np > 0.0f) ? rs / denom : 0.0f;
    out[0] = cl + rl;
    out[1] = cl;
    out[2] = rl;
}

extern "C" void kernel_launch(void* const* d_in, const int* in_sizes, int n_in,
                              void* d_out, int out_size, void* d_ws, size_t ws_size,
                              hipStream_t stream) {
    const float* cls_pred = (const float*)d_in[0];   // [B,A,80]
    const float* reg_pred = (const float*)d_in[1];   // [B,A,4]
    const float* anchors  = (const float*)d_in[2];   // [A,4]
    const float* gt_boxes = (const float*)d_in[3];   // [B,G,4]
    const int*   gt_labels= (const int*)d_in[4];     // [B,G]
    float* out = (float*)d_out;

    float* accum = (float*)d_ws;                     // 3 floats
    unsigned char* valid = (unsigned char*)d_ws + 16;// B*A bytes

    hipMemsetAsync(d_ws, 0, 16, stream);

    const int blocks1 = (B_CNT * A_CNT) / 256;       // 3072
    match_kernel<<<blocks1, 256, 0, stream>>>(cls_pred, reg_pred, anchors, gt_boxes,
                                              gt_labels, valid, accum);

    focal_kernel<<<FOCAL_BLOCKS, 256, 0, stream>>>(cls_pred, valid, accum);

    finalize_kernel<<<1, 1, 0, stream>>>(accum, out);
}